// Round 1
// baseline (377.036 us; speedup 1.0000x reference)
//
#include <hip/hip_runtime.h>

#define T_SEQ   2048
#define DH      128
#define WINDOW  512
#define BM      64
#define BN      64
#define SCALE_F 0.08838834764831845f   // 1/sqrt(128)

typedef unsigned short ushort_t;
typedef __attribute__((ext_vector_type(8))) unsigned short ushort8;
typedef __attribute__((ext_vector_type(4))) unsigned short ushort4v;
typedef __attribute__((ext_vector_type(4))) float float4v;
typedef __attribute__((ext_vector_type(8))) __bf16 bf16x8;

union U8 { ushort8 us; bf16x8 bf; };

__device__ __forceinline__ unsigned short f2bf(float f) {
  union { float f; unsigned u; } x; x.f = f;
  unsigned r = x.u + 0x7FFFu + ((x.u >> 16) & 1u);   // RNE
  return (unsigned short)(r >> 16);
}

// LDS pitches (ushort units). Rows 16B-aligned for ds_read_b128; strides give
// <=2-way bank aliasing (free on gfx950 per m136).
#define KP 136   // K tile [64 key][128 d], pitch 136 -> 272B rows
#define VP 72    // Vt     [128 d][64 key], pitch 72  -> 144B rows
#define PP 72    // P      [16 m][64 k] per wave

__global__ __launch_bounds__(256)
void swa_fwd(const float* __restrict__ qg, const float* __restrict__ kg,
             const float* __restrict__ vg, float* __restrict__ og)
{
  __shared__ ushort_t ldsK[64 * KP];        // 17408 B
  __shared__ ushort_t ldsVt[128 * VP];      // 18432 B
  __shared__ ushort_t ldsP[4 * 16 * PP];    //  9216 B

  const int qt   = blockIdx.x;
  const int bh   = blockIdx.y;
  const int tid  = threadIdx.x;
  const int wv   = tid >> 6;
  const int lane = tid & 63;
  const int quad = lane >> 4;
  const int ln16 = lane & 15;

  const size_t base = (size_t)bh * (T_SEQ * DH);
  const float* qb = qg + base;
  const float* kb = kg + base;
  const float* vb = vg + base;
  float*       ob = og + base;

  const int i0w = qt * BM + wv * 16;        // this wave's first q row

  // ---- Q fragments in registers, A-layout: m=ln16, k=ks*32+quad*8+j ----
  bf16x8 qf[4];
  {
    const float* qrow = qb + (size_t)(i0w + ln16) * DH + quad * 8;
#pragma unroll
    for (int ks = 0; ks < 4; ++ks) {
      float4v a = *(const float4v*)(qrow + ks * 32);
      float4v b = *(const float4v*)(qrow + ks * 32 + 4);
      U8 u;
      u.us[0]=f2bf(a[0]); u.us[1]=f2bf(a[1]); u.us[2]=f2bf(a[2]); u.us[3]=f2bf(a[3]);
      u.us[4]=f2bf(b[0]); u.us[5]=f2bf(b[1]); u.us[6]=f2bf(b[2]); u.us[7]=f2bf(b[3]);
      qf[ks] = u.bf;
    }
  }

  // O accumulator, C-layout rows = quad*4+reg (same mapping as S rows)
  float4v Oacc[8];
#pragma unroll
  for (int n = 0; n < 8; ++n) Oacc[n] = (float4v)(0.0f);
  float m_i[4] = {-1e30f, -1e30f, -1e30f, -1e30f};
  float l_i[4] = {0.f, 0.f, 0.f, 0.f};

  const int kt0 = (qt >= 8) ? (qt - 8) : 0;
  for (int kt = kt0; kt <= qt; ++kt) {
    // ---- stage K tile -> LDS [key][d] bf16 (coalesced 64B segments) ----
    {
      const int row = tid >> 2;
      const int c4  = (tid & 3) * 4;
      const float* src = kb + ((size_t)kt * BN + row) * DH + c4;
      ushort_t* dst = ldsK + row * KP + c4;
#pragma unroll
      for (int u = 0; u < 8; ++u) {
        float4v a = *(const float4v*)(src + u * 16);
        ushort4v h;
        h[0]=f2bf(a[0]); h[1]=f2bf(a[1]); h[2]=f2bf(a[2]); h[3]=f2bf(a[3]);
        *(ushort4v*)(dst + u * 16) = h;
      }
    }
    // ---- stage V tile transposed -> Vt[d][key] via register 4x4 blocks ----
    {
      const int cb  = tid >> 3;     // d block  (0..31)
      const int rb0 = tid & 7;      // key block
      const float* vsrc = vb + (size_t)kt * BN * DH;
#pragma unroll
      for (int it = 0; it < 2; ++it) {
        const int rb = rb0 + it * 8;                 // 0..15 -> keys rb*4..+3
        const float* src = vsrc + (size_t)(rb * 4) * DH + cb * 4;
        float4v r0 = *(const float4v*)(src);
        float4v r1 = *(const float4v*)(src + DH);
        float4v r2 = *(const float4v*)(src + 2 * DH);
        float4v r3 = *(const float4v*)(src + 3 * DH);
#pragma unroll
        for (int c = 0; c < 4; ++c) {
          ushort4v h;
          h[0]=f2bf(r0[c]); h[1]=f2bf(r1[c]); h[2]=f2bf(r2[c]); h[3]=f2bf(r3[c]);
          *(ushort4v*)(ldsVt + (cb * 4 + c) * VP + rb * 4) = h;
        }
      }
    }
    __syncthreads();

    // ---- S = Q K^T : 16 MFMAs, C-layout col(key)=ln16+16nt, row(q)=quad*4+r ----
    float4v sv[4];
#pragma unroll
    for (int nt = 0; nt < 4; ++nt) {
      float4v acc = (float4v)(0.0f);
      const ushort_t* kp = ldsK + (nt * 16 + ln16) * KP + quad * 8;
#pragma unroll
      for (int ks = 0; ks < 4; ++ks) {
        U8 b; b.us = *(const ushort8*)(kp + ks * 32);
        acc = __builtin_amdgcn_mfma_f32_16x16x32_bf16(qf[ks], b.bf, acc, 0, 0, 0);
      }
      sv[nt] = acc;
    }

    // ---- mask + scale ----
#pragma unroll
    for (int nt = 0; nt < 4; ++nt) {
      const int j = kt * BN + nt * 16 + ln16;
#pragma unroll
      for (int r = 0; r < 4; ++r) {
        const int i = i0w + quad * 4 + r;
        const bool ok = (j <= i) && ((i - j) < WINDOW);
        sv[nt][r] = ok ? sv[nt][r] * SCALE_F : -1e30f;
      }
    }

    // ---- online softmax: row max (16-lane xor reduce), alpha, P=exp ----
    float alpha[4];
#pragma unroll
    for (int r = 0; r < 4; ++r) {
      float mt = fmaxf(fmaxf(sv[0][r], sv[1][r]), fmaxf(sv[2][r], sv[3][r]));
      mt = fmaxf(mt, __shfl_xor(mt, 1));
      mt = fmaxf(mt, __shfl_xor(mt, 2));
      mt = fmaxf(mt, __shfl_xor(mt, 4));
      mt = fmaxf(mt, __shfl_xor(mt, 8));
      const float mn = fmaxf(m_i[r], mt);
      alpha[r] = __expf(m_i[r] - mn);
      m_i[r] = mn;
    }

    ushort_t* pb = ldsP + wv * (16 * PP);
#pragma unroll
    for (int r = 0; r < 4; ++r) {
      float ps = 0.f;
#pragma unroll
      for (int nt = 0; nt < 4; ++nt) {
        const float p = __expf(sv[nt][r] - m_i[r]);
        ps += p;
        pb[(quad * 4 + r) * PP + nt * 16 + ln16] = f2bf(p);  // C->A via LDS
      }
      l_i[r] = l_i[r] * alpha[r] + ps;   // per-lane partial over its 4 cols
#pragma unroll
      for (int n = 0; n < 8; ++n) Oacc[n][r] *= alpha[r];
    }

    // ---- O += P V : P read back in A-layout, Vt gives contiguous B frags ----
#pragma unroll
    for (int ks = 0; ks < 2; ++ks) {
      U8 a; a.us = *(const ushort8*)(pb + ln16 * PP + ks * 32 + quad * 8);
#pragma unroll
      for (int n = 0; n < 8; ++n) {
        U8 b; b.us = *(const ushort8*)(ldsVt + (n * 16 + ln16) * VP + ks * 32 + quad * 8);
        Oacc[n] = __builtin_amdgcn_mfma_f32_16x16x32_bf16(a.bf, b.bf, Oacc[n], 0, 0, 0);
      }
    }
    __syncthreads();   // before next tile's staging overwrites ldsK/ldsVt
  }

  // ---- epilogue: reduce l across the 16-lane group, normalize, store ----
  float linv[4];
#pragma unroll
  for (int r = 0; r < 4; ++r) {
    float s = l_i[r];
    s += __shfl_xor(s, 1);
    s += __shfl_xor(s, 2);
    s += __shfl_xor(s, 4);
    s += __shfl_xor(s, 8);
    linv[r] = 1.0f / s;
  }
  float* orow = ob + (size_t)(i0w + quad * 4) * DH + ln16;
#pragma unroll
  for (int r = 0; r < 4; ++r) {
#pragma unroll
    for (int n = 0; n < 8; ++n) {
      orow[(size_t)r * DH + n * 16] = Oacc[n][r] * linv[r];
    }
  }
}

extern "C" void kernel_launch(void* const* d_in, const int* in_sizes, int n_in,
                              void* d_out, int out_size, void* d_ws, size_t ws_size,
                              hipStream_t stream) {
  const float* q = (const float*)d_in[0];
  const float* k = (const float*)d_in[1];
  const float* v = (const float*)d_in[2];
  float* o = (float*)d_out;
  const int bh_count = in_sizes[0] / (T_SEQ * DH);   // B*H = 64
  dim3 grid(T_SEQ / BM, bh_count);
  swa_fwd<<<grid, 256, 0, stream>>>(q, k, v, o);
}

// Round 2
// 283.213 us; speedup vs baseline: 1.3313x; 1.3313x over previous
//
#include <hip/hip_runtime.h>

#define T_SEQ   2048
#define DH      128
#define WINDOW  512
#define BM      128          // q rows per block (8 waves x 16)
#define BN      64           // keys per k-tile
#define NT      32           // k-tiles per bh  (T_SEQ/BN)
#define TILE_US 16384        // ushorts per (K,Vt) tile pair in ws
#define SCALE_F 0.08838834764831845f

typedef unsigned short ushort_t;
typedef __attribute__((ext_vector_type(8))) unsigned short ushort8;
typedef __attribute__((ext_vector_type(4))) unsigned short ushort4v;
typedef __attribute__((ext_vector_type(4))) float float4v;
typedef __attribute__((ext_vector_type(8))) __bf16 bf16x8;

union U8 { ushort8 us; bf16x8 bf; };

__device__ __forceinline__ unsigned short f2bf(float f) {
  union { float f; unsigned u; } x; x.f = f;
  unsigned r = x.u + 0x7FFFu + ((x.u >> 16) & 1u);   // RNE
  return (unsigned short)(r >> 16);
}

__device__ __forceinline__ void async16(const ushort_t* g, ushort_t* l) {
  __builtin_amdgcn_global_load_lds(
      (const __attribute__((address_space(1))) unsigned int*)g,
      (__attribute__((address_space(3))) unsigned int*)l, 16, 0, 0);
}

// ---------------- pre-pass: K,V fp32 -> bf16 swizzled tiles in ws ----------
// ws layout per tile t = bh*32+kt (16384 ushorts = 32 KB):
//   [0..8191]    K  [key 0..63][d 0..127], 16B-block col swizzle c8 ^= key&7
//   [8192..]     Vt [d 0..127][key 0..63], 16B-block col swizzle c8 ^= d&7
__global__ __launch_bounds__(256)
void pack_kv(const float* __restrict__ kg, const float* __restrict__ vg,
             ushort_t* __restrict__ ws)
{
  const int tile = blockIdx.x;             // bh*32 + kt
  const int tid  = threadIdx.x;
  const size_t src = (size_t)tile * (BN * DH);
  const float* kb = kg + src;
  const float* vb = vg + src;
  ushort_t* wk = ws + (size_t)tile * TILE_US;
  ushort_t* wv = wk + 8192;

  // K: 1024 blocks of 8 elements
#pragma unroll
  for (int rep = 0; rep < 4; ++rep) {
    const int b   = rep * 256 + tid;
    const int key = b >> 4;
    const int c8  = b & 15;
    const float* s = kb + key * DH + c8 * 8;
    float4v a = *(const float4v*)s;
    float4v c = *(const float4v*)(s + 4);
    ushort8 h;
    h[0]=f2bf(a[0]); h[1]=f2bf(a[1]); h[2]=f2bf(a[2]); h[3]=f2bf(a[3]);
    h[4]=f2bf(c[0]); h[5]=f2bf(c[1]); h[6]=f2bf(c[2]); h[7]=f2bf(c[3]);
    *(ushort8*)(wk + key * DH + ((c8 ^ (key & 7)) << 3)) = h;
  }

  // V transpose via 4x4 register blocks (round-1 verified pattern)
  const int cb  = tid >> 3;        // d block 0..31
  const int rb0 = tid & 7;
#pragma unroll
  for (int it = 0; it < 2; ++it) {
    const int rb = rb0 + it * 8;   // key block: keys rb*4 .. rb*4+3
    const float* s = vb + (size_t)(rb * 4) * DH + cb * 4;
    float4v r0 = *(const float4v*)(s);
    float4v r1 = *(const float4v*)(s + DH);
    float4v r2 = *(const float4v*)(s + 2 * DH);
    float4v r3 = *(const float4v*)(s + 3 * DH);
#pragma unroll
    for (int c = 0; c < 4; ++c) {
      const int d = cb * 4 + c;
      ushort4v h;
      h[0]=f2bf(r0[c]); h[1]=f2bf(r1[c]); h[2]=f2bf(r2[c]); h[3]=f2bf(r3[c]);
      *(ushort4v*)(wv + d * BN + (((rb >> 1) ^ (d & 7)) << 3) + (rb & 1) * 4) = h;
    }
  }
}

// ---------------- attention: flash with MFMA, async staged bf16 tiles -----
#define PP 72    // P pitch per wave (padded; small traffic)

__global__ __launch_bounds__(512)
void swa_fwd(const float* __restrict__ qg, const ushort_t* __restrict__ ws,
             float* __restrict__ og)
{
  __shared__ ushort_t lds[TILE_US + 8 * 16 * PP];   // 32KB KV + 9KB P = 51200B
  ushort_t* ldsK  = lds;            // [64 key][128 d] swizzled
  ushort_t* ldsVt = lds + 8192;     // [128 d][64 key] swizzled
  ushort_t* ldsP  = lds + TILE_US;

  const int qt   = blockIdx.x;
  const int bh   = blockIdx.y;
  const int tid  = threadIdx.x;
  const int wv   = tid >> 6;
  const int lane = tid & 63;
  const int quad = lane >> 4;
  const int ln16 = lane & 15;
  const int l7   = ln16 & 7;

  const size_t base = (size_t)bh * (T_SEQ * DH);
  const float* qb = qg + base;
  float*       ob = og + base;
  const ushort_t* wsb = ws + (size_t)bh * NT * TILE_US;

  const int i0w = qt * BM + wv * 16;   // this wave's first q row

  // Q fragments (A-layout: m=ln16, k=ks*32+quad*8+j), scale folded in
  bf16x8 qf[4];
  {
    const float* qrow = qb + (size_t)(i0w + ln16) * DH + quad * 8;
#pragma unroll
    for (int ks = 0; ks < 4; ++ks) {
      float4v a = *(const float4v*)(qrow + ks * 32);
      float4v b = *(const float4v*)(qrow + ks * 32 + 4);
      U8 u;
      u.us[0]=f2bf(a[0]*SCALE_F); u.us[1]=f2bf(a[1]*SCALE_F);
      u.us[2]=f2bf(a[2]*SCALE_F); u.us[3]=f2bf(a[3]*SCALE_F);
      u.us[4]=f2bf(b[0]*SCALE_F); u.us[5]=f2bf(b[1]*SCALE_F);
      u.us[6]=f2bf(b[2]*SCALE_F); u.us[7]=f2bf(b[3]*SCALE_F);
      qf[ks] = u.bf;
    }
  }

  float4v Oacc[8];
#pragma unroll
  for (int n = 0; n < 8; ++n) Oacc[n] = (float4v)(0.0f);
  float m_i[4] = {-1e30f, -1e30f, -1e30f, -1e30f};
  float l_i[4] = {0.f, 0.f, 0.f, 0.f};

  const int lo  = qt * BM - (WINDOW - 1);
  const int kt0 = (lo > 0) ? (lo >> 6) : 0;
  const int kt1 = (qt * BM + BM - 1) >> 6;      // = 2*qt+1

  for (int kt = kt0; kt <= kt1; ++kt) {
    // ---- stage K+Vt tile pair: 32 KB via global_load_lds (4 rounds) ----
    {
      const ushort_t* wt = wsb + (size_t)kt * TILE_US;
#pragma unroll
      for (int rd = 0; rd < 4; ++rd) {
        const int off = (rd * 512 + tid) * 8;   // 16B per lane, lane-contig
        async16(wt + off, lds + off);
      }
    }
    __syncthreads();   // drains vmcnt incl. global_load_lds

    const int j0 = kt * BN;
    // wave-level skip: does this wave's row range intersect this tile?
    const bool wave_active = (j0 <= i0w + 15) && (i0w - j0 - 63 < WINDOW);
    if (wave_active) {
      // ---- S = Q K^T (C-layout: col=key ln16+16nt, row=q quad*4+r) ----
      float4v sv[4];
#pragma unroll
      for (int nt = 0; nt < 4; ++nt) {
        float4v acc = (float4v)(0.0f);
        const ushort_t* kp = ldsK + (nt * 16 + ln16) * DH;
#pragma unroll
        for (int ks = 0; ks < 4; ++ks) {
          U8 b; b.us = *(const ushort8*)(kp + (((ks * 4 + quad) ^ l7) << 3));
          acc = __builtin_amdgcn_mfma_f32_16x16x32_bf16(qf[ks], b.bf, acc, 0, 0, 0);
        }
        sv[nt] = acc;
      }

      // ---- mask (only on edge tiles) ----
      const bool need_mask = (j0 + 63 > i0w) || ((i0w + 15) - j0 >= WINDOW);
      if (need_mask) {
#pragma unroll
        for (int nt = 0; nt < 4; ++nt) {
          const int j = j0 + nt * 16 + ln16;
#pragma unroll
          for (int r = 0; r < 4; ++r) {
            const int i = i0w + quad * 4 + r;
            const bool ok = (j <= i) && ((i - j) < WINDOW);
            sv[nt][r] = ok ? sv[nt][r] : -1e30f;
          }
        }
      }

      // ---- online softmax ----
      float alpha[4];
#pragma unroll
      for (int r = 0; r < 4; ++r) {
        float mt = fmaxf(fmaxf(sv[0][r], sv[1][r]), fmaxf(sv[2][r], sv[3][r]));
        mt = fmaxf(mt, __shfl_xor(mt, 1));
        mt = fmaxf(mt, __shfl_xor(mt, 2));
        mt = fmaxf(mt, __shfl_xor(mt, 4));
        mt = fmaxf(mt, __shfl_xor(mt, 8));
        const float mn = fmaxf(m_i[r], mt);
        alpha[r] = __expf(m_i[r] - mn);
        m_i[r] = mn;
      }

      ushort_t* pb = ldsP + wv * (16 * PP);
#pragma unroll
      for (int r = 0; r < 4; ++r) {
        float ps = 0.f;
#pragma unroll
        for (int nt = 0; nt < 4; ++nt) {
          const float p = __expf(sv[nt][r] - m_i[r]);
          ps += p;
          pb[(quad * 4 + r) * PP + nt * 16 + ln16] = f2bf(p);  // C->A via LDS
        }
        l_i[r] = l_i[r] * alpha[r] + ps;
#pragma unroll
        for (int n = 0; n < 8; ++n) Oacc[n][r] *= alpha[r];
      }

      // ---- O += P V ----
#pragma unroll
      for (int ks = 0; ks < 2; ++ks) {
        U8 a; a.us = *(const ushort8*)(pb + ln16 * PP + ks * 32 + quad * 8);
#pragma unroll
        for (int n = 0; n < 8; ++n) {
          const ushort_t* vp = ldsVt + (n * 16 + ln16) * BN;
          U8 b; b.us = *(const ushort8*)(vp + (((ks * 4 + quad) ^ l7) << 3));
          Oacc[n] = __builtin_amdgcn_mfma_f32_16x16x32_bf16(a.bf, b.bf, Oacc[n], 0, 0, 0);
        }
      }
    }
    __syncthreads();   // all waves done with LDS before next tile staging
  }

  // ---- epilogue ----
  float linv[4];
#pragma unroll
  for (int r = 0; r < 4; ++r) {
    float s = l_i[r];
    s += __shfl_xor(s, 1);
    s += __shfl_xor(s, 2);
    s += __shfl_xor(s, 4);
    s += __shfl_xor(s, 8);
    linv[r] = 1.0f / s;
  }
  float* orow = ob + (size_t)(i0w + quad * 4) * DH + ln16;
#pragma unroll
  for (int r = 0; r < 4; ++r) {
#pragma unroll
    for (int n = 0; n < 8; ++n) {
      orow[(size_t)r * DH + n * 16] = Oacc[n][r] * linv[r];
    }
  }
}

extern "C" void kernel_launch(void* const* d_in, const int* in_sizes, int n_in,
                              void* d_out, int out_size, void* d_ws, size_t ws_size,
                              hipStream_t stream) {
  const float* q = (const float*)d_in[0];
  const float* k = (const float*)d_in[1];
  const float* v = (const float*)d_in[2];
  float* o = (float*)d_out;
  const int bh_count = in_sizes[0] / (T_SEQ * DH);   // 64
  ushort_t* ws = (ushort_t*)d_ws;                    // needs 64 MB; ws_size is larger

  pack_kv<<<dim3(bh_count * NT), 256, 0, stream>>>(k, v, ws);
  swa_fwd<<<dim3(T_SEQ / BM, bh_count), 512, 0, stream>>>(q, ws, o);
}

// Round 3
// 280.102 us; speedup vs baseline: 1.3461x; 1.0111x over previous
//
#include <hip/hip_runtime.h>

#define T_SEQ   2048
#define DH      128
#define WINDOW  512
#define BM      128          // q rows per block = 4 waves x 32
#define BN      64           // keys per tile
#define NT      32           // tiles per bh
#define TILE_US 16384        // ushorts per (K,Vt) tile pair (32 KB)
#define SCALE_LOG2E 0.12751744250f   // (1/sqrt(128)) * log2(e)  -> use exp2

typedef unsigned short ushort_t;
typedef __attribute__((ext_vector_type(8))) unsigned short ushort8;
typedef __attribute__((ext_vector_type(4))) unsigned short ushort4v;
typedef __attribute__((ext_vector_type(4))) float float4v;
typedef __attribute__((ext_vector_type(16))) float float16v;
typedef __attribute__((ext_vector_type(8))) __bf16 bf16x8;

union U8 { ushort8 us; bf16x8 bf; unsigned u[4]; };
union FU { float f; unsigned u; };

__device__ __forceinline__ unsigned short f2bf(float f) {
  FU x; x.f = f;
  unsigned r = x.u + 0x7FFFu + ((x.u >> 16) & 1u);   // RNE
  return (unsigned short)(r >> 16);
}

__device__ __forceinline__ void async16(const ushort_t* g, ushort_t* l) {
  __builtin_amdgcn_global_load_lds(
      (const __attribute__((address_space(1))) unsigned int*)g,
      (__attribute__((address_space(3))) unsigned int*)l, 16, 0, 0);
}

// ---------------------------------------------------------------------------
// pack_kv: fp32 K,V -> bf16 tile images in ws, via LDS bounce (all global
// writes coalesced). Per tile (32 KB): [0..8191] K[key][d] with 16B-block
// swizzle c8^=(key&7); [8192..16383] Vt[d][pos] where pos = key with bits
// 2,3 swapped (sigma order for lane-local P fragments) and block swizzle
// B^=(d&7).
// ---------------------------------------------------------------------------
__global__ __launch_bounds__(256)
void pack_kv(const float* __restrict__ kg, const float* __restrict__ vg,
             ushort_t* __restrict__ ws)
{
  __shared__ __align__(16) ushort_t sb[TILE_US];
  const int tile = blockIdx.x;
  const int tid  = threadIdx.x;
  const size_t src = (size_t)tile * (BN * DH);
  const float* kb = kg + src;
  const float* vb = vg + src;

  // K phase: coalesced reads, swizzled LDS writes (conflict-free pattern)
#pragma unroll
  for (int rep = 0; rep < 4; ++rep) {
    const int b   = rep * 256 + tid;
    const int key = b >> 4;
    const int c8  = b & 15;
    const float* s = kb + key * DH + c8 * 8;
    float4v a = *(const float4v*)s;
    float4v c = *(const float4v*)(s + 4);
    U8 h;
    h.us[0]=f2bf(a[0]); h.us[1]=f2bf(a[1]); h.us[2]=f2bf(a[2]); h.us[3]=f2bf(a[3]);
    h.us[4]=f2bf(c[0]); h.us[5]=f2bf(c[1]); h.us[6]=f2bf(c[2]); h.us[7]=f2bf(c[3]);
    *(ushort8*)(sb + key * DH + ((c8 ^ (key & 7)) << 3)) = h.us;
  }

  // V phase: register 4x4 transpose, write into sigma+swizzle layout in LDS
  {
    const int cb  = tid >> 3;     // d block 0..31
    const int rb0 = tid & 7;
#pragma unroll
    for (int it = 0; it < 2; ++it) {
      const int rb = rb0 + it * 8;           // keys rb*4 .. rb*4+3
      const float* s = vb + (size_t)(rb * 4) * DH + cb * 4;
      float4v r0 = *(const float4v*)(s);
      float4v r1 = *(const float4v*)(s + DH);
      float4v r2 = *(const float4v*)(s + 2 * DH);
      float4v r3 = *(const float4v*)(s + 3 * DH);
      const int B    = (rb & 1) | ((rb >> 2) << 1);   // 16B-block index 0..7
      const int off4 = ((rb >> 1) & 1) << 2;          // half-block offset
#pragma unroll
      for (int c = 0; c < 4; ++c) {
        const int d = cb * 4 + c;
        ushort4v h;
        h[0]=f2bf(r0[c]); h[1]=f2bf(r1[c]); h[2]=f2bf(r2[c]); h[3]=f2bf(r3[c]);
        *(ushort4v*)(sb + 8192 + d * BN + ((B ^ (d & 7)) << 3) + off4) = h;
      }
    }
  }
  __syncthreads();

  // copy out: fully coalesced 16B/lane linear
  ushort_t* wt = ws + (size_t)tile * TILE_US;
#pragma unroll
  for (int rep = 0; rep < 8; ++rep) {
    const int off = (rep * 256 + tid) * 8;
    *(ushort8*)(wt + off) = *(const ushort8*)(sb + off);
  }
}

// ---------------------------------------------------------------------------
// swa_fwd: flash attention, S^T formulation with 32x32x16 MFMA.
//   S^T = K Q^T  (A=K frag, B=Q frag)  -> C-layout: col=q, row=key
//   O^T = V^T P^T (A=Vt frag, B=P frag) -> P B-frag is LANE-LOCAL thanks to
//   the sigma key order baked into Vt storage. No P LDS buffer, no shuffles.
// ---------------------------------------------------------------------------
__global__ __launch_bounds__(256, 3)
void swa_fwd(const float* __restrict__ qg, const ushort_t* __restrict__ ws,
             float* __restrict__ og)
{
  __shared__ __align__(16) ushort_t lds[TILE_US];   // 32 KB: K | Vt

  const int qt   = (gridDim.x - 1) - blockIdx.x;    // heavy blocks first
  const int bh   = blockIdx.y;
  const int tid  = threadIdx.x;
  const int wv   = tid >> 6;
  const int lane = tid & 63;
  const int l32  = lane & 31;
  const int half = lane >> 5;
  const int l7   = l32 & 7;

  const size_t base = (size_t)bh * (T_SEQ * DH);
  const float* qb = qg + base;
  float*       ob = og + base;
  const ushort_t* wsb = ws + (size_t)bh * NT * TILE_US;

  const int i0w = qt * BM + wv * 32;   // wave's first q row (M=32 per wave)
  const int iq  = i0w + l32;           // this lane's q row

  // Q B-frags: B[k=d][n=q], lane n=l32, k = ks*16 + half*8 + j. Scale*log2e folded.
  bf16x8 qf[8];
  {
    const float* qrow = qb + (size_t)iq * DH + half * 8;
#pragma unroll
    for (int ks = 0; ks < 8; ++ks) {
      float4v a = *(const float4v*)(qrow + ks * 16);
      float4v b = *(const float4v*)(qrow + ks * 16 + 4);
      U8 u;
      u.us[0]=f2bf(a[0]*SCALE_LOG2E); u.us[1]=f2bf(a[1]*SCALE_LOG2E);
      u.us[2]=f2bf(a[2]*SCALE_LOG2E); u.us[3]=f2bf(a[3]*SCALE_LOG2E);
      u.us[4]=f2bf(b[0]*SCALE_LOG2E); u.us[5]=f2bf(b[1]*SCALE_LOG2E);
      u.us[6]=f2bf(b[2]*SCALE_LOG2E); u.us[7]=f2bf(b[3]*SCALE_LOG2E);
      qf[ks] = u.bf;
    }
  }

  float16v O[4];
#pragma unroll
  for (int dc = 0; dc < 4; ++dc) O[dc] = (float16v)(0.0f);
  float m = -1e30f, l = 0.f;

  const int lo  = qt * BM - (WINDOW - 1);
  const int kt0 = (lo > 0) ? (lo >> 6) : 0;
  const int kt1 = 2 * qt + 1;

  for (int kt = kt0; kt <= kt1; ++kt) {
    // stage 32 KB tile (K + Vt) via async direct-to-LDS
    {
      const ushort_t* wt = wsb + (size_t)kt * TILE_US;
#pragma unroll
      for (int rd = 0; rd < 8; ++rd) {
        const int off = (rd * 256 + tid) * 8;
        async16(wt + off, lds + off);
      }
    }
    __syncthreads();

    const int j0 = kt * BN;
    const bool active = (j0 <= i0w + 31) && (i0w - j0 - 63 < WINDOW);
    if (active) {
      // ---- S^T: 2 key-chunks x 8 k-steps of 32x32x16 ----
      float16v sv[2];
#pragma unroll
      for (int c = 0; c < 2; ++c) {
        float16v acc = (float16v)(0.0f);
        const ushort_t* krow = lds + (c * 32 + l32) * DH;
#pragma unroll
        for (int ks = 0; ks < 8; ++ks) {
          U8 a; a.us = *(const ushort8*)(krow + (((2 * ks + half) ^ l7) << 3));
          acc = __builtin_amdgcn_mfma_f32_32x32x16_bf16(a.bf, qf[ks], acc, 0, 0, 0);
        }
        sv[c] = acc;
      }

      // ---- mask (edge tiles only). row(key)=(reg&3)+8*(reg>>2)+4*half ----
      const bool full = (j0 + 63 <= i0w) && ((i0w + 31) - j0 < WINDOW);
      if (!full) {
#pragma unroll
        for (int c = 0; c < 2; ++c) {
#pragma unroll
          for (int r = 0; r < 16; ++r) {
            const int j = j0 + c * 32 + (r & 3) + 8 * (r >> 2) + 4 * half;
            const bool ok = (j <= iq) && ((iq - j) < WINDOW);
            sv[c][r] = ok ? sv[c][r] : -1e30f;
          }
        }
      }

      // ---- online softmax (log2 domain; one q row per lane) ----
      float mt = sv[0][0];
#pragma unroll
      for (int r = 1; r < 16; ++r) mt = fmaxf(mt, sv[0][r]);
#pragma unroll
      for (int r = 0; r < 16; ++r) mt = fmaxf(mt, sv[1][r]);
      mt = fmaxf(mt, __shfl_xor(mt, 32));
      const float mn = fmaxf(m, mt);
      const float alpha = __builtin_amdgcn_exp2f(m - mn);
      m = mn;

      float ps = 0.f;
      unsigned pk[2][8];
#pragma unroll
      for (int c = 0; c < 2; ++c) {
#pragma unroll
        for (int rg = 0; rg < 8; ++rg) {
          FU p0, p1;
          p0.f = __builtin_amdgcn_exp2f(sv[c][2 * rg]     - m);
          p1.f = __builtin_amdgcn_exp2f(sv[c][2 * rg + 1] - m);
          p0.u &= 0xFFFF0000u; p1.u &= 0xFFFF0000u;   // truncate to bf16
          ps += p0.f + p1.f;                           // l matches P exactly
          pk[c][rg] = (p0.u >> 16) | p1.u;
        }
      }
      l = l * alpha + ps;
#pragma unroll
      for (int dc = 0; dc < 4; ++dc)
#pragma unroll
        for (int r = 0; r < 16; ++r) O[dc][r] *= alpha;

      // ---- O^T += V^T P^T : B-frag for k-step s = sv regs [8(s&1)..+7] ----
#pragma unroll
      for (int s = 0; s < 4; ++s) {
        const int c = s >> 1, o = (s & 1) * 4;
        U8 b;
        b.u[0] = pk[c][o]; b.u[1] = pk[c][o + 1];
        b.u[2] = pk[c][o + 2]; b.u[3] = pk[c][o + 3];
        const int blk = ((2 * s + half) ^ l7) << 3;
#pragma unroll
        for (int dc = 0; dc < 4; ++dc) {
          U8 a; a.us = *(const ushort8*)(lds + 8192 + (dc * 32 + l32) * BN + blk);
          O[dc] = __builtin_amdgcn_mfma_f32_32x32x16_bf16(a.bf, b.bf, O[dc], 0, 0, 0);
        }
      }
    }
    __syncthreads();
  }

  // ---- epilogue: fold halves of l, normalize, store ----
  l += __shfl_xor(l, 32);
  const float linv = 1.0f / l;
  float* orow = ob + (size_t)iq * DH;
#pragma unroll
  for (int dc = 0; dc < 4; ++dc) {
#pragma unroll
    for (int g = 0; g < 4; ++g) {
      float4v o4;
      o4[0] = O[dc][g * 4 + 0] * linv; o4[1] = O[dc][g * 4 + 1] * linv;
      o4[2] = O[dc][g * 4 + 2] * linv; o4[3] = O[dc][g * 4 + 3] * linv;
      *(float4v*)(orow + dc * 32 + g * 8 + half * 4) = o4;
    }
  }
}

extern "C" void kernel_launch(void* const* d_in, const int* in_sizes, int n_in,
                              void* d_out, int out_size, void* d_ws, size_t ws_size,
                              hipStream_t stream) {
  const float* q = (const float*)d_in[0];
  const float* k = (const float*)d_in[1];
  const float* v = (const float*)d_in[2];
  float* o = (float*)d_out;
  const int bh_count = in_sizes[0] / (T_SEQ * DH);   // 64
  ushort_t* ws = (ushort_t*)d_ws;                    // 64 MB used

  pack_kv<<<dim3(bh_count * NT), 256, 0, stream>>>(k, v, ws);
  swa_fwd<<<dim3(T_SEQ / BM, bh_count), 256, 0, stream>>>(q, ws, o);
}